// Round 1
// baseline (4223.920 us; speedup 1.0000x reference)
//
#include <hip/hip_runtime.h>

#define BB 8
#define LL 512
#define DD 512
#define HH 8
#define DH 64
#define BLD (BB*LL*DD)      // 2097152

typedef _Float16 f16;
typedef f16 f16x8 __attribute__((ext_vector_type(8)));
typedef f16 f16x4 __attribute__((ext_vector_type(4)));
typedef float f32x4 __attribute__((ext_vector_type(4)));

// MFMA 16x16x32 f16 fragment layouts (per cdna4 docs, m89/m120-verified family):
//   A: lane holds A[m=lane&15][k=(lane>>4)*8 + j], j=0..7
//   B: lane holds B[k=(lane>>4)*8 + j][n=lane&15]
//   D: lane reg r holds D[row=(lane>>4)*4 + r][col=lane&15]

__device__ inline f16x8 ldg_cvt8(const float* __restrict__ p){
  float4 a = *(const float4*)p;
  float4 b = *(const float4*)(p+4);
  f16x8 r;
  r[0]=(f16)a.x; r[1]=(f16)a.y; r[2]=(f16)a.z; r[3]=(f16)a.w;
  r[4]=(f16)b.x; r[5]=(f16)b.y; r[6]=(f16)b.z; r[7]=(f16)b.w;
  return r;
}
__device__ inline f16x8 ldg_f16x8(const f16* __restrict__ p){ return *(const f16x8*)p; }

// ---------------- K1 / K4: Y[M,N] = X[M,K] @ W[N,K]^T + bias, f16-MFMA ----------------
// MODE 0: q proj -> scale 1/8, store f16 qh[b][h][l][e]
// MODE 1: k proj -> store f16 kh[b][h][l][e]
// MODE 2: v proj -> store f16 vth[b][h][e][l]   (transposed, ki-contiguous rows)
// MODE 3: out proj -> store fp32 d_out[m*512+n]
template<int MODE>
__global__ __launch_bounds__(256) void gemm_xwT(const float* __restrict__ X,
        const float* __restrict__ W, const float* __restrict__ bias,
        f16* __restrict__ oh, float* __restrict__ of)
{
  int tid = threadIdx.x;
  int w = tid >> 6, lane = tid & 63;
  int l15 = lane & 15, quad = lane >> 4;
  int m0 = blockIdx.x*64 + w*16;
  int n0 = blockIdx.y*64;
  const float* arow = X + (size_t)(m0 + l15)*DD;
  const float* brow[4];
#pragma unroll
  for(int nt=0;nt<4;nt++) brow[nt] = W + (size_t)(n0 + nt*16 + l15)*DD;
  f32x4 acc[4];
#pragma unroll
  for(int nt=0;nt<4;nt++) acc[nt] = (f32x4){0.f,0.f,0.f,0.f};
  for(int ks=0; ks<16; ks++){
    int k0 = ks*32 + quad*8;
    f16x8 a = ldg_cvt8(arow + k0);
#pragma unroll
    for(int nt=0;nt<4;nt++){
      f16x8 b = ldg_cvt8(brow[nt] + k0);
      acc[nt] = __builtin_amdgcn_mfma_f32_16x16x32_f16(a, b, acc[nt], 0,0,0);
    }
  }
#pragma unroll
  for(int nt=0;nt<4;nt++){
    int n = n0 + nt*16 + l15;     // D col = lane&15
    float bb = bias[n];
#pragma unroll
    for(int r=0;r<4;r++){
      int m = m0 + quad*4 + r;    // D row
      float v = acc[nt][r] + bb;
      if (MODE==0) v *= 0.125f;
      if (MODE==3){
        of[(size_t)m*DD + n] = v;
      } else {
        int b_ = m >> 9, l = m & 511;
        int h  = n >> 6, e = n & 63;
        size_t idx;
        if (MODE==2) idx = ((size_t)(b_*HH+h)*DH + e)*LL + l;
        else         idx = ((size_t)(b_*HH+h)*LL + l)*DH + e;
        oh[idx] = (f16)v;
      }
    }
  }
}

// ---------------- K2: fully fused per-(b,qj) attention ----------------
// One 512-thread block per (b, qj). Phases:
//  0. load q-row (8h x 64e) ; structure slice (512ki x 64e) fp32->f16 into LDS,
//     XOR-swizzled in 16B chunks: sS[ki*64 + ((ec ^ (ki&7))<<3) + j]  (f16 units)
//  1. qs[h][x] = sum_y qrow[h][y]*Wsk[y][x]        (64 MAC/thread)
//  2. scores[h][ki] = q.k (global kh, L2-hot) + qs.struct (LDS)   thread ki=w*64+l, 8 h
//  3. softmax over full 512-ki rows (shfl + 8x8 LDS cross-wave), attn -> LDS f16 [8][520]
//     h==0 row -> attn0 global (fp32)
//  4. PV: ctx1[h=w][e=l] = sum_ki attn[h][ki]*vth[h][e][ki]  (global vth rows, L2-hot)
//  5. t[h][e]  = sum_ki attn[h][ki]*struct[ki][e]  (LDS) -> 32-way partials
//     (partials overlay the struct LDS buffer: exact 64 KB fit)
//  6. ctx2[h][d] = sum_e t[h][e]*Wsv[d][e] ; ctx = ctx1 + ctx2 + bsv
__global__ __launch_bounds__(512, 4) void fused_attn(
    const f16* __restrict__ qh, const f16* __restrict__ kh, const f16* __restrict__ vth,
    const float* __restrict__ st, const float* __restrict__ Wsk,
    const float* __restrict__ Wsv, const float* __restrict__ bsv,
    float* __restrict__ ctx, float* __restrict__ attn0)
{
  __shared__ f16 sS[512*64];        // 64 KB struct tile (later reused as fp32 t-partials)
  __shared__ f16 qrow[8*64];
  __shared__ f16 qsr[8*64];
  __shared__ f16 attnl[8*520];      // rows padded to 520 f16 (1040 B, 16B-aligned)
  __shared__ float redm[64];        // [h][wave]
  __shared__ float redl[64];
  __shared__ float tbuf[8*64];

  const int t = threadIdx.x;
  const int w = t>>6, l = t&63;
  const int qj = blockIdx.x, b = blockIdx.y;

  // ---- phase 0: q row + struct tile -> LDS ----
  if (t < 64){
    int h = t>>3, c = t&7;
    *(f16x8*)&qrow[h*64 + c*8] = ldg_f16x8(qh + ((size_t)(b*HH+h)*LL + qj)*DH + c*8);
  }
  const float* sbase = st + ((size_t)b*LL + qj)*(size_t)(LL*DH);
#pragma unroll
  for(int i=0;i<8;i++){
    int idx = t + i*512;            // 4096 chunks of 8 floats
    int ki = idx>>3, ec = idx&7;
    const float* p = sbase + ki*64 + ec*8;
    float4 a = *(const float4*)p;
    float4 c = *(const float4*)(p+4);
    f16x8 hv;
    hv[0]=(f16)a.x; hv[1]=(f16)a.y; hv[2]=(f16)a.z; hv[3]=(f16)a.w;
    hv[4]=(f16)c.x; hv[5]=(f16)c.y; hv[6]=(f16)c.z; hv[7]=(f16)c.w;
    *(f16x8*)&sS[ki*64 + ((ec ^ (ki&7))<<3)] = hv;
  }
  __syncthreads();

  // ---- phase 1: qs = qrow @ Wsk  (thread = (h=w, x=l)) ----
  {
    float acc = 0.f;
#pragma unroll 8
    for(int y=0;y<64;y++) acc += (float)qrow[w*64+y] * Wsk[y*64 + l];
    qsr[w*64 + l] = (f16)acc;
  }
  __syncthreads();

  // ---- phase 2: scores (thread owns ki = w*64+l, all 8 h) ----
  const int ki = w*64 + l;
  const int kx3 = (ki&7)<<3;
  float s[8];
#pragma unroll
  for(int h=0;h<8;h++) s[h]=0.f;
  const f16* srow = &sS[ki*64];
  const f16* khb  = kh + (size_t)b*HH*LL*DH + (size_t)ki*DH;
#pragma unroll
  for(int ec=0;ec<8;ec++){
    f16x8 c8 = *(const f16x8*)&srow[(ec<<3) ^ kx3];
#pragma unroll
    for(int h=0;h<8;h++){
      f16x8 k8 = ldg_f16x8(khb + (size_t)h*LL*DH + ec*8);
      f16x8 q8 = *(const f16x8*)&qrow[h*64 + ec*8];
      f16x8 g8 = *(const f16x8*)&qsr[h*64 + ec*8];
      float acc = s[h];
#pragma unroll
      for(int j=0;j<8;j++)
        acc += (float)q8[j]*(float)k8[j] + (float)g8[j]*(float)c8[j];
      s[h] = acc;
    }
  }

  // ---- phase 3: softmax over 512-ki rows ----
  float p[8];
  {
#pragma unroll
    for(int h=0;h<8;h++){
      float v = s[h];
#pragma unroll
      for(int msk=1; msk<64; msk<<=1) v = fmaxf(v, __shfl_xor(v, msk));
      if (l==0) redm[h*8+w] = v;
    }
    __syncthreads();
    float M[8];
#pragma unroll
    for(int h=0;h<8;h++){
      float4 r0 = *(const float4*)&redm[h*8];
      float4 r1 = *(const float4*)&redm[h*8+4];
      M[h] = fmaxf(fmaxf(fmaxf(r0.x,r0.y),fmaxf(r0.z,r0.w)),
                   fmaxf(fmaxf(r1.x,r1.y),fmaxf(r1.z,r1.w)));
    }
#pragma unroll
    for(int h=0;h<8;h++){
      float v = __expf(s[h]-M[h]);
      p[h] = v;
#pragma unroll
      for(int msk=1; msk<64; msk<<=1) v += __shfl_xor(v, msk);
      if (l==0) redl[h*8+w] = v;
    }
    __syncthreads();
#pragma unroll
    for(int h=0;h<8;h++){
      float4 r0 = *(const float4*)&redl[h*8];
      float4 r1 = *(const float4*)&redl[h*8+4];
      float tot = (r0.x+r0.y+r0.z+r0.w)+(r1.x+r1.y+r1.z+r1.w);
      p[h] = p[h] / tot;
    }
  }
#pragma unroll
  for(int h=0;h<8;h++) attnl[h*520 + ki] = (f16)p[h];
  attn0[((size_t)(b*LL+qj))*LL + ki] = p[0];
  __syncthreads();

  // ---- phase 4: PV (thread = (h=w, e=l), full 512-ki dot off global vth) ----
  float c1a=0.f,c1b=0.f,c1c=0.f,c1d=0.f;
  const f16* vrow = vth + ((size_t)(b*HH + w)*DH + l)*LL;
#pragma unroll 16
  for(int kc=0;kc<64;kc++){
    f16x8 v8 = ldg_f16x8(vrow + kc*8);
    f16x8 a8 = *(const f16x8*)&attnl[w*520 + kc*8];
    c1a += (float)a8[0]*(float)v8[0] + (float)a8[4]*(float)v8[4];
    c1b += (float)a8[1]*(float)v8[1] + (float)a8[5]*(float)v8[5];
    c1c += (float)a8[2]*(float)v8[2] + (float)a8[6]*(float)v8[6];
    c1d += (float)a8[3]*(float)v8[3] + (float)a8[7]*(float)v8[7];
  }
  const float c1 = (c1a+c1b)+(c1c+c1d);

  // ---- phase 5: t = attn @ struct (LDS), thread = (e-quad q4 = l&15, ki-run g) ----
  const int q4 = l&15, run = l>>4;
  const int ki0 = w*64 + run*16;
  const int ecx = q4>>1, hf = (q4&1)*4;
  f16x4 sv[16];
#pragma unroll
  for(int kk=0;kk<16;kk++){
    int kia = ki0 + kk;               // kia&7 == kk&7 (ki0 multiple of 16)
    sv[kk] = *(const f16x4*)&sS[kia*64 + ((ecx ^ (kk&7))<<3) + hf];
  }
  float ta[8][4];
#pragma unroll
  for(int h=0;h<8;h++){ ta[h][0]=0.f; ta[h][1]=0.f; ta[h][2]=0.f; ta[h][3]=0.f; }
#pragma unroll
  for(int h=0;h<8;h++){
    f16x8 a0 = *(const f16x8*)&attnl[h*520 + ki0];
    f16x8 a1 = *(const f16x8*)&attnl[h*520 + ki0 + 8];
#pragma unroll
    for(int kk=0;kk<8;kk++){
      float av = (float)a0[kk];
#pragma unroll
      for(int j=0;j<4;j++) ta[h][j] += av * (float)sv[kk][j];
    }
#pragma unroll
    for(int kk=0;kk<8;kk++){
      float av = (float)a1[kk];
#pragma unroll
      for(int j=0;j<4;j++) ta[h][j] += av * (float)sv[8+kk][j];
    }
  }
  __syncthreads();                      // all struct reads done; overlay partials
  float* part = (float*)sS;             // 32 groups x 8 h x 64 e x 4 B = 64 KB
  const int g = w*4 + run;
#pragma unroll
  for(int h=0;h<8;h++){
    float4 vv; vv.x=ta[h][0]; vv.y=ta[h][1]; vv.z=ta[h][2]; vv.w=ta[h][3];
    *(float4*)&part[(size_t)(g*8+h)*64 + q4*4] = vv;
  }
  __syncthreads();
  {
    float acc2 = 0.f;
#pragma unroll
    for(int gg=0; gg<32; gg++) acc2 += part[(size_t)(gg*8+w)*64 + l];
    tbuf[w*64 + l] = acc2;
  }
  __syncthreads();

  // ---- phase 6: ctx2 = t @ Wsv^T, output (thread = (h=w, d=l)) ----
  {
    float a3=0.f, b3=0.f;
    const float4* W4 = (const float4*)(Wsv + l*64);
#pragma unroll
    for(int e4=0;e4<16;e4+=2){
      float4 wv0 = W4[e4];
      float4 tt0 = *(const float4*)&tbuf[w*64 + e4*4];
      a3 += wv0.x*tt0.x + wv0.y*tt0.y + wv0.z*tt0.z + wv0.w*tt0.w;
      float4 wv1 = W4[e4+1];
      float4 tt1 = *(const float4*)&tbuf[w*64 + e4*4 + 4];
      b3 += wv1.x*tt1.x + wv1.y*tt1.y + wv1.z*tt1.z + wv1.w*tt1.w;
    }
    ctx[((size_t)(b*LL+qj))*DD + w*64 + l] = c1 + (a3+b3) + bsv[l];
  }
}

// ---------------- launch ----------------
extern "C" void kernel_launch(void* const* d_in, const int* in_sizes, int n_in,
                              void* d_out, int out_size, void* d_ws, size_t ws_size,
                              hipStream_t stream)
{
  const float* query = (const float*)d_in[0];
  const float* key   = (const float*)d_in[1];
  const float* value = (const float*)d_in[2];
  const float* st    = (const float*)d_in[3];
  const float* Wq = (const float*)d_in[4];  const float* bq = (const float*)d_in[5];
  const float* Wk = (const float*)d_in[6];  const float* bk = (const float*)d_in[7];
  const float* Wv = (const float*)d_in[8];  const float* bv = (const float*)d_in[9];
  const float* Wsk= (const float*)d_in[10];
  const float* Wsv= (const float*)d_in[12]; const float* bsv= (const float*)d_in[13];
  const float* Wo = (const float*)d_in[14]; const float* bo = (const float*)d_in[15];

  char* ws = (char*)d_ws;
  f16* qh   = (f16*)(ws);                  //  4 MB  q/8, [b][h][l][e]
  f16* kh   = (f16*)(ws + 4194304);        //  4 MB  [b][h][l][e]
  f16* vth  = (f16*)(ws + 8388608);        //  4 MB  [b][h][e][l]
  float* ctx = (float*)(ws + 12582912);    //  8 MB  [b][l][h*64+e]
  float* outp  = (float*)d_out;
  float* attn0 = outp + BLD;

  dim3 blk(256);
  gemm_xwT<0><<<dim3(64,8),blk,0,stream>>>(query, Wq, bq, qh, nullptr);
  gemm_xwT<1><<<dim3(64,8),blk,0,stream>>>(key,   Wk, bk, kh, nullptr);
  gemm_xwT<2><<<dim3(64,8),blk,0,stream>>>(value, Wv, bv, vth, nullptr);
  fused_attn<<<dim3(512,8), dim3(512), 0, stream>>>(qh, kh, vth, st, Wsk, Wsv, bsv, ctx, attn0);
  gemm_xwT<3><<<dim3(64,8),blk,0,stream>>>(ctx, Wo, bo, nullptr, outp);
}